// Round 4
// baseline (76.903 us; speedup 1.0000x reference)
//
#include <hip/hip_runtime.h>

// Spherical harmonics Y_l^m, l = 0..3, m = -l..l, complex (re, im), packed as
// [B, N, N, 16, 2] float32.  Reference recurrences collapsed to closed form:
//   ct = z/r, st = sqrt(max(1-ct^2,0)), cos/sin(m*phi) via Chebyshev from
//   c1 = x/rho, s1 = y/rho  (rho = sqrt(x^2+y^2); phi=atan2(y,x)=0 when rho=0).
// Condon-Shortley phase is baked into the sign of each coefficient.

constexpr int PTS_PER_BLOCK = 256;
constexpr int LDS_STRIDE    = 33;  // 32 floats/point + 1 pad -> conflict-free LDS

__global__ __launch_bounds__(256) void spharm16_kernel(const float* __restrict__ X,
                                                       float* __restrict__ out,
                                                       int npts) {
    __shared__ float lds[PTS_PER_BLOCK * LDS_STRIDE];  // 33792 B -> 4 blocks/CU

    const int t = threadIdx.x;
    const int p = blockIdx.x * PTS_PER_BLOCK + t;
    const int pc = (p < npts) ? p : (npts - 1);  // clamp (grid is exact here)

    const float x = X[3 * pc + 0];
    const float y = X[3 * pc + 1];
    const float z = X[3 * pc + 2];

    // --- angles -----------------------------------------------------------
    const float r2   = x * x + y * y + z * z;
    const float rinv = rsqrtf(r2);
    const float ct   = z * rinv;                    // cos(theta)
    const float ct2  = ct * ct;
    const float st2  = fmaxf(1.0f - ct2, 0.0f);
    const float st   = sqrtf(st2);                  // sin(theta) >= 0

    const float rho2 = x * x + y * y;
    const float pinv = rsqrtf(rho2);
    const bool  okp  = rho2 > 0.0f;
    const float c1   = okp ? x * pinv : 1.0f;       // cos(phi)
    const float s1   = okp ? y * pinv : 0.0f;       // sin(phi)
    const float c2   = c1 * c1 - s1 * s1;           // cos(2phi)
    const float s2   = 2.0f * c1 * s1;              // sin(2phi)
    const float c3   = c2 * c1 - s2 * s1;           // cos(3phi)
    const float s3   = s2 * c1 + c2 * s1;           // sin(3phi)

    // --- normalized Legendre bases (CS phase folded into signs below) -----
    const float S1  = 0.34549414947133547f * st;                  // n11 * st
    const float B10 = 0.48860251190291992f * ct;                  // n10 * P10
    const float B20 = 0.63078313050504031f * (1.5f * ct2 - 0.5f); // n20 * P20
    const float T21 = 0.77254840404637910f * ct * st;             // 3*n21*ct*st
    const float B22 = 0.38627420202318955f * st2;                 // 3*n22*st^2
    const float B30 = 0.74635266518023080f * ct * (2.5f * ct2 - 1.5f);
    const float B31 = 0.32318018411248776f * st * (1.0f - 5.0f * ct2);
    const float B32 = 1.02198547643188850f * ct * st2;            // 15*n32*ct*st^2
    const float T33 = 0.41722382363278404f * st2 * st;            // 15*n33*st^3

    // --- stage 32 floats/point in LDS (stride 33: write bank = (t+c)&31) ---
    const int b = t * LDS_STRIDE;
    lds[b +  0] = 0.28209479177387814f;  lds[b +  1] = 0.0f;        // (0, 0)
    lds[b +  2] =  S1 * c1;              lds[b +  3] = -S1 * s1;    // (1,-1)
    lds[b +  4] =  B10;                  lds[b +  5] = 0.0f;        // (1, 0)
    lds[b +  6] = -S1 * c1;              lds[b +  7] = -S1 * s1;    // (1, 1)
    lds[b +  8] =  B22 * c2;             lds[b +  9] = -B22 * s2;   // (2,-2)
    lds[b + 10] =  T21 * c1;             lds[b + 11] = -T21 * s1;   // (2,-1)
    lds[b + 12] =  B20;                  lds[b + 13] = 0.0f;        // (2, 0)
    lds[b + 14] = -T21 * c1;             lds[b + 15] = -T21 * s1;   // (2, 1)
    lds[b + 16] =  B22 * c2;             lds[b + 17] =  B22 * s2;   // (2, 2)
    lds[b + 18] =  T33 * c3;             lds[b + 19] = -T33 * s3;   // (3,-3)
    lds[b + 20] =  B32 * c2;             lds[b + 21] = -B32 * s2;   // (3,-2)
    lds[b + 22] = -B31 * c1;             lds[b + 23] =  B31 * s1;   // (3,-1)
    lds[b + 24] =  B30;                  lds[b + 25] = 0.0f;        // (3, 0)
    lds[b + 26] =  B31 * c1;             lds[b + 27] =  B31 * s1;   // (3, 1)
    lds[b + 28] =  B32 * c2;             lds[b + 29] =  B32 * s2;   // (3, 2)
    lds[b + 30] = -T33 * c3;             lds[b + 31] = -T33 * s3;   // (3, 3)

    __syncthreads();

    // --- coalesced drain: lane-consecutive float4 -> 1 KiB/wave/instr ------
    float4* __restrict__ out4 = reinterpret_cast<float4*>(out);
    const int base4 = blockIdx.x * (PTS_PER_BLOCK * 8);
    const int nf4   = npts * 8;  // total float4s
    if (base4 + PTS_PER_BLOCK * 8 <= nf4) {      // block-uniform fast path
#pragma unroll
        for (int j = 0; j < 8; ++j) {
            const int i4 = j * 256 + t;          // local float4 index, 0..2047
            const int pl = i4 >> 3;              // local point
            const int c  = (i4 & 7) * 4;         // first float of this quad
            const int a  = pl * LDS_STRIDE + c;
            out4[base4 + i4] = make_float4(lds[a], lds[a + 1], lds[a + 2], lds[a + 3]);
        }
    } else {
#pragma unroll
        for (int j = 0; j < 8; ++j) {
            const int i4 = j * 256 + t;
            const int g4 = base4 + i4;
            if (g4 < nf4) {
                const int pl = i4 >> 3;
                const int c  = (i4 & 7) * 4;
                const int a  = pl * LDS_STRIDE + c;
                out4[g4] = make_float4(lds[a], lds[a + 1], lds[a + 2], lds[a + 3]);
            }
        }
    }
}

extern "C" void kernel_launch(void* const* d_in, const int* in_sizes, int n_in,
                              void* d_out, int out_size, void* d_ws, size_t ws_size,
                              hipStream_t stream) {
    const float* X = (const float*)d_in[0];
    float* out = (float*)d_out;
    const int npts = in_sizes[0] / 3;                       // 524288
    const int blocks = (npts + PTS_PER_BLOCK - 1) / PTS_PER_BLOCK;  // 2048
    spharm16_kernel<<<blocks, PTS_PER_BLOCK, 0, stream>>>(X, out, npts);
}

// Round 5
// 76.209 us; speedup vs baseline: 1.0091x; 1.0091x over previous
//
#include <hip/hip_runtime.h>

// Spherical harmonics Y_l^m, l = 0..3, complex (re,im), packed [B,N,N,16,2] f32.
// Closed-form Legendre + Chebyshev cos/sin(m*phi); CS phase baked into signs.
//
// LDS layout: float4 slots [256 points][8 quads], physical quad = q ^ (t&7).
// 16-B aligned -> ds_write_b128 / ds_read_b128; XOR swizzle -> each 8-lane
// group covers all 32 banks exactly once per b128 phase (conflict-free).
// 32 KB LDS -> 5 blocks/CU (20 waves/CU).

constexpr int PTS_PER_BLOCK = 256;

__global__ __launch_bounds__(256) void spharm16_kernel(const float* __restrict__ X,
                                                       float4* __restrict__ out4,
                                                       int npts) {
    __shared__ float4 lds[PTS_PER_BLOCK * 8];  // 32768 B

    const int t = threadIdx.x;
    const int p = blockIdx.x * PTS_PER_BLOCK + t;
    const int pc = (p < npts) ? p : (npts - 1);  // clamp (grid exact here)

    const float x = X[3 * pc + 0];
    const float y = X[3 * pc + 1];
    const float z = X[3 * pc + 2];

    // --- angles -----------------------------------------------------------
    const float r2   = x * x + y * y + z * z;
    const float rinv = rsqrtf(r2);
    const float ct   = z * rinv;                    // cos(theta)
    const float ct2  = ct * ct;
    const float st2  = fmaxf(1.0f - ct2, 0.0f);
    const float st   = sqrtf(st2);                  // sin(theta) >= 0

    const float rho2 = x * x + y * y;
    const float pinv = rsqrtf(rho2);
    const bool  okp  = rho2 > 0.0f;
    const float c1   = okp ? x * pinv : 1.0f;       // cos(phi)
    const float s1   = okp ? y * pinv : 0.0f;       // sin(phi)
    const float c2   = c1 * c1 - s1 * s1;           // cos(2phi)
    const float s2   = 2.0f * c1 * s1;              // sin(2phi)
    const float c3   = c2 * c1 - s2 * s1;           // cos(3phi)
    const float s3   = s2 * c1 + c2 * s1;           // sin(3phi)

    // --- normalized Legendre bases (CS phase folded into signs) -----------
    const float S1  = 0.34549414947133547f * st;                  // n11 * st
    const float B10 = 0.48860251190291992f * ct;
    const float B20 = 0.63078313050504031f * (1.5f * ct2 - 0.5f);
    const float T21 = 0.77254840404637910f * ct * st;
    const float B22 = 0.38627420202318955f * st2;
    const float B30 = 0.74635266518023080f * ct * (2.5f * ct2 - 1.5f);
    const float B31 = 0.32318018411248776f * st * (1.0f - 5.0f * ct2);
    const float B32 = 1.02198547643188850f * ct * st2;
    const float T33 = 0.41722382363278404f * st2 * st;

    const float S1c1 = S1 * c1,  S1s1 = S1 * s1;
    const float T21c1 = T21 * c1, T21s1 = T21 * s1;
    const float B22c2 = B22 * c2, B22s2 = B22 * s2;
    const float B31c1 = B31 * c1, B31s1 = B31 * s1;
    const float B32c2 = B32 * c2, B32s2 = B32 * s2;
    const float T33c3 = T33 * c3, T33s3 = T33 * s3;

    // --- stage: 8 ds_write_b128, XOR-swizzled slot (constant reg indices) --
    const int wb = t * 8;
    const int sw = t & 7;
    lds[wb + (0 ^ sw)] = make_float4(0.28209479177387814f, 0.0f, S1c1, -S1s1); // (0,0),(1,-1)
    lds[wb + (1 ^ sw)] = make_float4(B10, 0.0f, -S1c1, -S1s1);                 // (1,0),(1,1)
    lds[wb + (2 ^ sw)] = make_float4(B22c2, -B22s2, T21c1, -T21s1);            // (2,-2),(2,-1)
    lds[wb + (3 ^ sw)] = make_float4(B20, 0.0f, -T21c1, -T21s1);               // (2,0),(2,1)
    lds[wb + (4 ^ sw)] = make_float4(B22c2, B22s2, T33c3, -T33s3);             // (2,2),(3,-3)
    lds[wb + (5 ^ sw)] = make_float4(B32c2, -B32s2, -B31c1, B31s1);            // (3,-2),(3,-1)
    lds[wb + (6 ^ sw)] = make_float4(B30, 0.0f, B31c1, B31s1);                 // (3,0),(3,1)
    lds[wb + (7 ^ sw)] = make_float4(B32c2, B32s2, -T33c3, -T33s3);            // (3,2),(3,3)

    __syncthreads();

    // --- drain: 8 x (ds_read_b128 + global_store_dwordx4), lane-coalesced --
    const int base4 = blockIdx.x * (PTS_PER_BLOCK * 8);
    const int nf4   = npts * 8;
    if (base4 + PTS_PER_BLOCK * 8 <= nf4) {      // block-uniform fast path
#pragma unroll
        for (int j = 0; j < 8; ++j) {
            const int i4 = j * 256 + t;          // local float4 index
            const int pl = i4 >> 3;              // local point
            const int c4 = i4 & 7;               // logical quad
            out4[base4 + i4] = lds[pl * 8 + (c4 ^ (pl & 7))];
        }
    } else {
#pragma unroll
        for (int j = 0; j < 8; ++j) {
            const int i4 = j * 256 + t;
            const int g4 = base4 + i4;
            if (g4 < nf4) {
                const int pl = i4 >> 3;
                const int c4 = i4 & 7;
                out4[g4] = lds[pl * 8 + (c4 ^ (pl & 7))];
            }
        }
    }
}

extern "C" void kernel_launch(void* const* d_in, const int* in_sizes, int n_in,
                              void* d_out, int out_size, void* d_ws, size_t ws_size,
                              hipStream_t stream) {
    const float* X = (const float*)d_in[0];
    float4* out4 = (float4*)d_out;
    const int npts = in_sizes[0] / 3;                       // 524288
    const int blocks = (npts + PTS_PER_BLOCK - 1) / PTS_PER_BLOCK;  // 2048
    spharm16_kernel<<<blocks, PTS_PER_BLOCK, 0, stream>>>(X, out4, npts);
}